// Round 17
// baseline (844.732 us; speedup 1.0000x reference)
//
#include <hip/hip_runtime.h>
#include <hip/hip_bf16.h>
#include <stdint.h>

typedef __attribute__((ext_vector_type(8))) short bf16x8;
typedef __attribute__((ext_vector_type(4))) float f32x4;

#define DEV __device__ __forceinline__
#define MFMA16(a, b, c) __builtin_amdgcn_mfma_f32_16x16x32_bf16(a, b, c, 0, 0, 0)

static constexpr int Bn = 4096;    // batch
static constexpr int Tn = 16;      // time steps
static constexpr int Vn = 512;     // vocab
static constexpr int En = 512;     // embed dim
static constexpr int Hn = 1024;    // hidden
static constexpr int G4 = 4096;    // 4*H

DEV unsigned short f2bf(float f) {
    union { float f; uint32_t u; } v; v.f = f;
    return (unsigned short)((v.u + 0x7fffu + ((v.u >> 16) & 1u)) >> 16);
}
DEV float bf2f(unsigned short h) {
    union { uint32_t u; float f; } v; v.u = (uint32_t)h << 16; return v.f;
}
DEV float sigmoidf_(float x) { return 1.f / (1.f + __expf(-x)); }
DEV float tanhf_(float x)    { return 1.f - 2.f / (1.f + __expf(2.f * x)); }

DEV bf16x8 cvt8(const float* p) {
    f32x4 a = *(const f32x4*)p;
    f32x4 b = *(const f32x4*)(p + 4);
    bf16x8 o;
    o[0] = (short)f2bf(a[0]); o[1] = (short)f2bf(a[1]);
    o[2] = (short)f2bf(a[2]); o[3] = (short)f2bf(a[3]);
    o[4] = (short)f2bf(b[0]); o[5] = (short)f2bf(b[1]);
    o[6] = (short)f2bf(b[2]); o[7] = (short)f2bf(b[3]);
    return o;
}

#define GLOAD16(s, d) __builtin_amdgcn_global_load_lds( \
    (const __attribute__((address_space(1))) uint32_t*)(s), \
    (__attribute__((address_space(3))) uint32_t*)(d), 16, 0, 0)

// ---------------------------------------------------------------------------
// lstm8 (R14/R16-exact, best known): 256x256-tile, BK=64, 1024 threads = 16
// waves (4M x 4N), 2-phase counted-vmcnt GEMM
//   gates^T = Whp8(perm,swz) @ Hin^T, K=1024  + fused LSTM epilogue.
// bf16 Cst + bf16 EGb, both read at EPILOGUE time only (R11 ledger lesson).
// Grid dim3(16,16): bx x-fastest -> XCD = bx%8 (B panel L2-local).
// LDS: A buf{0,1} @ ush {0,16384}, B buf{0,1} @ {32768,49152};
// XOR slot swizzle (r,c) -> r*64 + ((c>>3 ^ (r&7))<<3 | (c&7)).
// ---------------------------------------------------------------------------
__launch_bounds__(1024, 4)
__global__ void lstm8(const unsigned short* __restrict__ Whp8,
                      const unsigned short* __restrict__ Hin,
                      const unsigned short* __restrict__ EGb,
                      const int* __restrict__ target, int t,
                      unsigned short* __restrict__ CstF,
                      unsigned short* __restrict__ Hout)
{
    __shared__ __align__(16) unsigned short lds[65536];  // 128 KiB

    const int tid = threadIdx.x;
    const int l   = tid & 63;
    const int w   = tid >> 6;          // 0..15
    const int wm  = w >> 2, wn = w & 3;
    const int q   = l >> 4, c15 = l & 15;
    const int bx  = blockIdx.x, by = blockIdx.y;
    const int n0  = bx * 256;          // batch base
    const int U0  = by * 64;

    const int cBt = (((tid & 7) ^ ((tid >> 3) & 7)) << 3);
    const int sw0   = ((q ^ (c15 & 7)) << 3);
    const int offA0 = wm * 4096 + c15 * 64 + sw0;   // + i*1024 ; ^32 for ks1
    const int offB0 = wn * 4096 + c15 * 64 + sw0;   // + j*1024

    f32x4 acc[4][4];
#pragma unroll
    for (int i = 0; i < 4; i++)
#pragma unroll
        for (int j = 0; j < 4; j++) acc[i][j] = f32x4{0.f, 0.f, 0.f, 0.f};

    auto stA = [&](int kts, int cbuf) {
        const unsigned short* page =
            Whp8 + (((size_t)(by * 16 + kts) * 2) << 13);
#pragma unroll
        for (int h = 0; h < 2; h++)
            GLOAD16(page + h * 8192 + tid * 8,
                    &lds[cbuf * 16384 + h * 8192 + tid * 8]);
    };
    auto stB = [&](int kts, int cbuf) {
#pragma unroll
        for (int h = 0; h < 2; h++)
            GLOAD16(Hin + (size_t)(n0 + h * 128 + (tid >> 3)) * Hn
                        + kts * 64 + cBt,
                    &lds[32768 + cbuf * 16384 + h * 8192 + tid * 8]);
    };

    // ---- prologue: tile0 -> buf0, tile1 -> buf1 (4 loads each) ----
    stA(0, 0); stB(0, 0);
    stA(1, 1); stB(1, 1);
    asm volatile("s_waitcnt vmcnt(4)" ::: "memory");   // tile0 landed
    __builtin_amdgcn_s_barrier();

#pragma unroll 2
    for (int kt = 0; kt < 16; kt++) {
        const int cur = kt & 1;
        const unsigned short* Ab = &lds[cur * 16384];
        const unsigned short* Bb = &lds[32768 + cur * 16384];
        bf16x8 aF[4], bF[4];

        // ---- P1: ks = 0 ----
#pragma unroll
        for (int i = 0; i < 4; i++)
            aF[i] = *(const bf16x8*)&Ab[offA0 + i * 1024];
#pragma unroll
        for (int j = 0; j < 4; j++)
            bF[j] = *(const bf16x8*)&Bb[offB0 + j * 1024];
        __builtin_amdgcn_s_setprio(1);
#pragma unroll
        for (int i = 0; i < 4; i++)
#pragma unroll
            for (int j = 0; j < 4; j++)
                acc[i][j] = MFMA16(aF[i], bF[j], acc[i][j]);
        __builtin_amdgcn_s_setprio(0);

        // ---- P2: ks = 1 (slot offset ^32) ----
#pragma unroll
        for (int i = 0; i < 4; i++)
            aF[i] = *(const bf16x8*)&Ab[(offA0 ^ 32) + i * 1024];
#pragma unroll
        for (int j = 0; j < 4; j++)
            bF[j] = *(const bf16x8*)&Bb[(offB0 ^ 32) + j * 1024];
        __builtin_amdgcn_s_setprio(1);
#pragma unroll
        for (int i = 0; i < 4; i++)
#pragma unroll
            for (int j = 0; j < 4; j++)
                acc[i][j] = MFMA16(aF[i], bF[j], acc[i][j]);
        __builtin_amdgcn_s_setprio(0);
        __builtin_amdgcn_s_barrier();   // all reads of buf cur complete

        // ---- P3: stage kt+2 (clamped tail -> garbage, never read) ----
        const int kts = (kt + 2 < 16) ? (kt + 2) : 15;
        stA(kts, cur);
        stB(kts, cur);
        asm volatile("s_waitcnt vmcnt(4)" ::: "memory");  // kt+1 landed
        __builtin_amdgcn_s_barrier();
    }

    // ---- epilogue: LSTM pointwise (bf16 EGb gather, bf16 Cst RMW) ----
    int ids[4];
#pragma unroll
    for (int j = 0; j < 4; j++)
        ids[j] = (t > 0)
            ? target[(size_t)(n0 + wn * 64 + j * 16 + c15) * Tn + (t - 1)] : 0;

    unsigned short* sH = &lds[32768];  // B buf0: writes retired, none in flight
#pragma unroll
    for (int i = 0; i < 4; i++) {
        const int Uloc = wm * 16 + i * 4 + q;
#pragma unroll
        for (int j = 0; j < 4; j++) {
            uint2 egu = *(const uint2*)&EGb[(size_t)ids[j] * G4 + (U0 + Uloc) * 4];
            float e0 = bf2f((unsigned short)(egu.x & 0xffffu));
            float e1 = bf2f((unsigned short)(egu.x >> 16));
            float e2 = bf2f((unsigned short)(egu.y & 0xffffu));
            float e3 = bf2f((unsigned short)(egu.y >> 16));
            float ig = sigmoidf_(acc[i][j][0] + e0);
            float fg = sigmoidf_(acc[i][j][1] + e1);
            float gg = tanhf_  (acc[i][j][2] + e2);
            float og = sigmoidf_(acc[i][j][3] + e3);
            const size_t cidx =
                ((((size_t)(by * 16 + bx) * 16 + w) * 16 + i * 4 + j) << 6) + l;
            float cOld = bf2f(CstF[cidx]);
            float cNew = fg * cOld + ig * gg;
            float h    = og * tanhf_(cNew);
            CstF[cidx] = f2bf(cNew);
            const int bl = wn * 64 + j * 16 + c15;
            sH[bl * 64 + (Uloc ^ ((bl & 7) << 3))] = f2bf(h);
        }
    }
    __syncthreads();   // drains vmcnt(0) too (tail staging)
    {
        const int row  = tid >> 2;            // 0..255 batch-local
        const int part = tid & 3;
        size_t go = (size_t)(n0 + row) * Hn + U0;
#pragma unroll
        for (int s = 0; s < 2; s++) {
            const int slog = part * 2 + s;
            bf16x8 v = *(const bf16x8*)&sH[row * 64 + ((slog ^ (row & 7)) << 3)];
            *(bf16x8*)&Hout[go + slog * 8] = v;
        }
    }
}

// ---------------------------------------------------------------------------
// logits512: each block owns 128 rows x FULL vocab (512) -> no duplicate A
// staging (R16 staged each A panel twice for the two vocab halves) and the
// block emits the FINAL per-row loss (no partials kernel). BK=32, 1024
// threads = 16 waves (2M x 8N), per-wave 64x64, acc[4][4] (~100 VGPR -> 4
// waves/SIMD, the R13-proven TLP point). LDS: A dbuf 2x8KB @ ush {0,8192};
// B dbuf 2x32KB @ {8192, 24576}; 4-slot swizzle (r,c): slot (c>>3)^(r&3).
// Staging 3 gloads/tile (1 A + 2 B); waves 8..15 duplicate the A bytes so
// the vmcnt ledger stays uniform -> vmcnt(3). Grid 512 (row tiles).
// No max-subtract: |logit| <~ 58, f32-exp safe.
// ---------------------------------------------------------------------------
__launch_bounds__(1024, 4)
__global__ void logits512(const unsigned short* __restrict__ A,   // h history
                          const unsigned short* __restrict__ Wob,
                          const int* __restrict__ target,
                          float* __restrict__ lossT)
{
    __shared__ __align__(16) unsigned short lds[40960];  // 80 KiB staging
    __shared__ float redS[8 * 128];
    __shared__ float redT[8 * 128];
    __shared__ int   tgL[128];

    const int tid = threadIdx.x;
    const int l   = tid & 63;
    const int w   = tid >> 6;          // 0..15
    const int wm  = w >> 3, wn = w & 7;
    const int q   = l >> 4, c15 = l & 15;
    const int r0  = blockIdx.x * 128;  // global row base (ra = t*Bn + m)

    if (tid < 128) {
        int ra = r0 + tid;
        tgL[tid] = target[(size_t)(ra & (Bn - 1)) * Tn + (ra >> 12)];
    }

    // staging: thread covers (row, phys slot) holding logical slot ^(row&3)
    const int tA   = tid & 511;
    const int rowA = tA >> 2;                              // 0..127
    const int colA = (((tA & 3) ^ (rowA & 3)) << 3);       // logical col
    const int rowB = tid >> 2;                             // 0..255
    const int colB = (((tid & 3) ^ (rowB & 3)) << 3);
    // ds_read: logical slot q at row r -> phys q^(r&3); r&3 == c15&3
    const int swz  = ((q ^ (c15 & 3)) << 3);
    const int offA = (wm * 64 + c15) * 32 + swz;           // + i*512
    const int offB = (wn * 64 + c15) * 32 + swz;           // + j*512

    f32x4 acc[4][4];
#pragma unroll
    for (int i = 0; i < 4; i++)
#pragma unroll
        for (int j = 0; j < 4; j++) acc[i][j] = f32x4{0.f, 0.f, 0.f, 0.f};

    auto stage = [&](int kts, int cbuf) {
        GLOAD16(A + (size_t)(r0 + rowA) * Hn + kts * 32 + colA,
                &lds[cbuf * 4096 + tA * 8]);
#pragma unroll
        for (int R = 0; R < 2; R++)
            GLOAD16(Wob + (size_t)(R * 256 + rowB) * Hn + kts * 32 + colB,
                    &lds[8192 + cbuf * 16384 + R * 8192 + tid * 8]);
    };

    stage(0, 0);
    stage(1, 1);
    asm volatile("s_waitcnt vmcnt(3)" ::: "memory");   // tile0 landed
    __builtin_amdgcn_s_barrier();

#pragma unroll 2
    for (int kt = 0; kt < 32; kt++) {
        const int cur = kt & 1;
        const unsigned short* Ab = &lds[cur * 4096];
        const unsigned short* Bb = &lds[8192 + cur * 16384];
        bf16x8 aF[4], bF[4];

#pragma unroll
        for (int i = 0; i < 4; i++)
            aF[i] = *(const bf16x8*)&Ab[offA + i * 512];
#pragma unroll
        for (int j = 0; j < 4; j++)
            bF[j] = *(const bf16x8*)&Bb[offB + j * 512];
        __builtin_amdgcn_s_setprio(1);
#pragma unroll
        for (int i = 0; i < 4; i++)
#pragma unroll
            for (int j = 0; j < 4; j++)
                acc[i][j] = MFMA16(aF[i], bF[j], acc[i][j]);
        __builtin_amdgcn_s_setprio(0);
        __builtin_amdgcn_s_barrier();   // all reads of buf cur complete

        const int kts = (kt + 2 < 32) ? (kt + 2) : 31;  // clamped tail
        stage(kts, cur);
        asm volatile("s_waitcnt vmcnt(3)" ::: "memory");  // kt+1 landed
        __builtin_amdgcn_s_barrier();
    }

    // ---- epilogue: per-row Sexp / target-logit (full vocab in block) ----
    // acc[i][j][rr]: row_loc = wm*64 + i*16 + q*4 + rr,
    //               vocab   = wn*64 + j*16 + c15.
#pragma unroll
    for (int i = 0; i < 4; i++)
#pragma unroll
        for (int rr = 0; rr < 4; rr++) {
            const int rloc = wm * 64 + i * 16 + q * 4 + rr;
            const int tg = tgL[rloc];
            float ps = 0.f, tv = 0.f;
#pragma unroll
            for (int j = 0; j < 4; j++) {
                float v = acc[i][j][rr];
                ps += __expf(v);
                int col = wn * 64 + j * 16 + c15;
                tv += (col == tg) ? v : 0.f;
            }
#pragma unroll
            for (int d = 1; d < 16; d <<= 1) {
                ps += __shfl_xor(ps, d);
                tv += __shfl_xor(tv, d);
            }
            if (c15 == 0) {
                redS[wn * 128 + rloc] = ps;
                redT[wn * 128 + rloc] = tv;
            }
        }
    __syncthreads();
    if (tid < 128) {
        float se = 0.f, tv = 0.f;
#pragma unroll
        for (int k = 0; k < 8; k++) {
            se += redS[k * 128 + tid];
            tv += redT[k * 128 + tid];
        }
        lossT[r0 + tid] = __logf(se) - tv;
    }
}

// ---------------------------------------------------------------------------
// bf16 GEMM (m97-style): C[M][N] = A[M][K] * Bw[N][K]^T
// EPI=0: Out = acc (+biasp), f32.  EPI=2: Outb = bf16(acc (+biasp)).
// ---------------------------------------------------------------------------
template <int BM, int BN, int EPI>
__launch_bounds__(256, 2)
__global__ void gemm_k(const unsigned short* __restrict__ A, int lda,
                       const unsigned short* __restrict__ Bw, int ldb,
                       int K,
                       const float* __restrict__ biasp,
                       float* __restrict__ Out,
                       unsigned short* __restrict__ Outb, int ldo)
{
    constexpr int BK = 32;
    constexpr int WM = BM / 2, WN = BN / 2;
    constexpr int MI = WM / 16, NJ = WN / 16;

    __shared__ __align__(16) unsigned short sA[BM * BK];
    __shared__ __align__(16) unsigned short sB[BN * BK];

    const int tid = threadIdx.x;
    const int l   = tid & 63;
    const int w   = tid >> 6;
    const int wm  = w >> 1, wn = w & 1;
    const int m0  = blockIdx.y * BM;
    const int n0  = blockIdx.x * BN;

    f32x4 acc[MI][NJ];
#pragma unroll
    for (int i = 0; i < MI; i++)
#pragma unroll
        for (int j = 0; j < NJ; j++) acc[i][j] = f32x4{0.f, 0.f, 0.f, 0.f};

    const int srow = l >> 2;
    const int scol = (l & 3) * 8;
    const int q    = l >> 4;
    const int c15  = l & 15;

    for (int k0 = 0; k0 < K; k0 += BK) {
#pragma unroll
        for (int c = 0; c < BM / 64; c++)
            GLOAD16(A + (size_t)(m0 + c * 64 + w * 16 + srow) * lda + k0 + scol,
                    &sA[(c * 64 + w * 16) * BK]);
#pragma unroll
        for (int c = 0; c < BN / 64; c++)
            GLOAD16(Bw + (size_t)(n0 + c * 64 + w * 16 + srow) * ldb + k0 + scol,
                    &sB[(c * 64 + w * 16) * BK]);
        __syncthreads();

        bf16x8 aF[MI], bF[NJ];
#pragma unroll
        for (int i = 0; i < MI; i++)
            aF[i] = *(const bf16x8*)&sA[(wm * WM + i * 16 + c15) * BK + q * 8];
#pragma unroll
        for (int j = 0; j < NJ; j++)
            bF[j] = *(const bf16x8*)&sB[(wn * WN + j * 16 + c15) * BK + q * 8];
#pragma unroll
        for (int i = 0; i < MI; i++)
#pragma unroll
            for (int j = 0; j < NJ; j++)
                acc[i][j] = MFMA16(aF[i], bF[j], acc[i][j]);
        __syncthreads();
    }

#pragma unroll
    for (int j = 0; j < NJ; j++) {
        const int colp = n0 + wn * WN + j * 16 + c15;
        const float bj = biasp ? biasp[colp] : 0.f;
#pragma unroll
        for (int i = 0; i < MI; i++) {
            const size_t rb = (size_t)(m0 + wm * WM + i * 16 + 4 * q);
#pragma unroll
            for (int r = 0; r < 4; r++) {
                float vv = acc[i][j][r] + bj;
                if constexpr (EPI == 0) Out[(rb + r) * ldo + colp] = vv;
                else Outb[(rb + r) * ldo + colp] = f2bf(vv);
            }
        }
    }
}

// ---------------------------------------------------------------------------
// Fused prep + init: Wihp / Whp8 / bias / Wob / embb / Cst+Xh0 init.
// Block ranges: [0,1024) wih | [1024,3072) w8 | [3072,3088) bias
//   [3088,3344) wout | [3344,3472) emb | [3472,19856) init_state.
// ---------------------------------------------------------------------------
__global__ void prep_all(const float* __restrict__ Wih,
                         const float* __restrict__ Whh,
                         const float* __restrict__ bih,
                         const float* __restrict__ bhh,
                         const float* __restrict__ Wout,
                         const float* __restrict__ emb,
                         const float* __restrict__ enc,
                         unsigned short* __restrict__ Wihp,
                         unsigned short* __restrict__ Whp8,
                         float* __restrict__ biasp,
                         unsigned short* __restrict__ Wob,
                         unsigned short* __restrict__ embb,
                         unsigned short* __restrict__ CstF,
                         unsigned short* __restrict__ Xh0,
                         float* __restrict__ loss)
{
    const int b = blockIdx.x;
    if (b < 1024) {                       // Wihp[u*4+g][k] = W_ih[g*H+u][k]
        int i = b * 256 + threadIdx.x;    // 4096*64
        int n = i >> 6, kc = (i & 63) * 8;
        int g = n & 3, u = n >> 2;
        *(bf16x8*)&Wihp[(size_t)n * En + kc] =
            cvt8(Wih + (size_t)(g * Hn + u) * En + kc);
    } else if (b < 3072) {                // Whp8 slot-swizzled pages
        int idx = (b - 1024) * 256 + threadIdx.x;  // 0..524287
        int o = idx * 8;
        int p = o & 8191;
        int h = (o >> 13) & 1;
        int kt = (o >> 14) & 15;
        int by = o >> 18;
        int r = p >> 6;
        int slot = (p & 63) >> 3;
        int cl = ((slot ^ (r & 7)) << 3);
        int n = by * 256 + h * 128 + r;   // permuted gate row u*4+g
        int g = n & 3, u = n >> 2;
        *(bf16x8*)&Whp8[o] =
            cvt8(Whh + (size_t)(g * Hn + u) * Hn + kt * 64 + cl);
    } else if (b < 3088) {                // biasp
        int n = (b - 3072) * 256 + threadIdx.x;  // 4096
        int g = n & 3, u = n >> 2;
        biasp[n] = bih[g * Hn + u] + bhh[g * Hn + u];
    } else if (b < 3344) {                // Wob bf16
        int i = (b - 3088) * 256 + threadIdx.x;  // 65536
        size_t off = (size_t)i * 8;
        *(bf16x8*)&Wob[off] = cvt8(Wout + off);
    } else if (b < 3472) {                // embb bf16
        int i = (b - 3344) * 256 + threadIdx.x;  // 32768
        size_t off = (size_t)i * 8;
        *(bf16x8*)&embb[off] = cvt8(emb + off);
    } else {                              // init: Cst (epilogue layout) + Xh0
        int f = (b - 3472) * 256 + threadIdx.x;  // 0 .. 4194303
        int l = f & 63, q = l >> 4, c15 = l & 15;
        int ij = (f >> 6) & 15, i = ij >> 2, j = ij & 3;
        int w = (f >> 10) & 15, wm = w >> 2, wn = w & 3;
        int bx = (f >> 14) & 15, by = (f >> 18) & 15;
        int bb = bx * 256 + wn * 64 + j * 16 + c15;
        int U  = by * 64 + wm * 16 + i * 4 + q;
        CstF[f] = f2bf(enc[(size_t)bb * Hn + U]);
        if (f < Bn * Hn / 8) {
            int m = f >> 7, u8 = (f & 127) * 8;
            *(bf16x8*)&Xh0[(size_t)m * Hn + u8] =
                cvt8(enc + (size_t)m * Hn + u8);
        }
        if (f < Bn) loss[f] = 0.f;
    }
}

// LSE + NLL over bf16 logits (fallback path).
__global__ void lse_k(const unsigned short* __restrict__ lg,
                      const int* __restrict__ target, int t,
                      float* __restrict__ lossOut)
{
    int w = threadIdx.x >> 6, l = threadIdx.x & 63;
    int ra = blockIdx.x * 4 + w;
    const unsigned short* row = lg + (size_t)ra * Vn;
    bf16x8 v = *(const bf16x8*)&row[l * 8];
    float x0 = bf2f((unsigned short)v[0]), x1 = bf2f((unsigned short)v[1]);
    float x2 = bf2f((unsigned short)v[2]), x3 = bf2f((unsigned short)v[3]);
    float x4 = bf2f((unsigned short)v[4]), x5 = bf2f((unsigned short)v[5]);
    float x6 = bf2f((unsigned short)v[6]), x7 = bf2f((unsigned short)v[7]);
    float mx = fmaxf(fmaxf(fmaxf(x0, x1), fmaxf(x2, x3)),
                     fmaxf(fmaxf(x4, x5), fmaxf(x6, x7)));
#pragma unroll
    for (int d = 1; d < 64; d <<= 1) mx = fmaxf(mx, __shfl_xor(mx, d));
    float se = __expf(x0 - mx) + __expf(x1 - mx) + __expf(x2 - mx) +
               __expf(x3 - mx) + __expf(x4 - mx) + __expf(x5 - mx) +
               __expf(x6 - mx) + __expf(x7 - mx);
#pragma unroll
    for (int d = 1; d < 64; d <<= 1) se += __shfl_xor(se, d);
    if (l == 0) {
        int tg = target[(size_t)ra * Tn + t];
        lossOut[ra] += (mx + __logf(se)) - bf2f(row[tg]);
    }
}

// Batched finalize: out[m] = (1/16) sum_t lossT[t*Bn+m].
__global__ void finalize_b(const float* __restrict__ lossT,
                           float* __restrict__ out)
{
    int m = blockIdx.x * 256 + threadIdx.x;
    float s = 0.f;
#pragma unroll
    for (int k = 0; k < 16; k++) s += lossT[(size_t)k * Bn + m];
    out[m] = s * (1.f / 16.f);
}

__global__ void finalize_s(const float* __restrict__ loss,
                           float* __restrict__ out)
{
    int m = blockIdx.x * 256 + threadIdx.x;
    out[m] = loss[m] * (1.f / 16.f);
}

// ---------------------------------------------------------------------------
extern "C" void kernel_launch(void* const* d_in, const int* in_sizes, int n_in,
                              void* d_out, int out_size, void* d_ws, size_t ws_size,
                              hipStream_t stream)
{
    const float* enc    = (const float*)d_in[0];
    const int*   target = (const int*)d_in[1];
    const float* emb    = (const float*)d_in[2];
    const float* Wih    = (const float*)d_in[3];
    const float* Whh    = (const float*)d_in[4];
    const float* bih    = (const float*)d_in[5];
    const float* bhh    = (const float*)d_in[6];
    const float* Wout   = (const float*)d_in[7];
    float* out = (float*)d_out;
    (void)in_sizes; (void)n_in; (void)out_size;

    constexpr size_t SZ_Wihp  = (size_t)G4 * En * 2;
    constexpr size_t SZ_Whp8  = (size_t)G4 * Hn * 2;
    constexpr size_t SZ_Wob   = (size_t)Vn * Hn * 2;
    constexpr size_t SZ_biasp = (size_t)G4 * 4;
    constexpr size_t SZ_embb  = (size_t)Vn * En * 2;
    constexpr size_t SZ_EGb   = (size_t)Vn * G4 * 2;      // bf16
    constexpr size_t SZ_Cst   = (size_t)Bn * Hn * 2;      // bf16
    constexpr size_t SZ_H     = (size_t)Bn * Hn * 2;
    constexpr size_t SZ_LGS   = (size_t)Bn * Vn * 2;
    constexpr size_t SZ_LT    = (size_t)Bn * Tn * 4;
    auto pad = [](size_t b) { return (b + 255) & ~(size_t)255; };
    const size_t fixed = pad(SZ_Wihp) + pad(SZ_Whp8) + pad(SZ_Wob) +
                         pad(SZ_biasp) + pad(SZ_embb) + pad(SZ_EGb) +
                         pad(SZ_Cst);
    const size_t needB = fixed + 17 * pad(SZ_H) + pad(SZ_LGS) + pad(SZ_LT);
    const bool batched = ws_size >= needB;

    size_t off = 0;
    char* base = (char*)d_ws;
    auto alloc = [&](size_t bytes) -> void* {
        void* p = base + off; off += pad(bytes); return p;
    };
    unsigned short* Wihp  = (unsigned short*)alloc(SZ_Wihp);
    unsigned short* Whp8  = (unsigned short*)alloc(SZ_Whp8);
    unsigned short* Wob   = (unsigned short*)alloc(SZ_Wob);
    float*          biasp = (float*)alloc(SZ_biasp);
    unsigned short* embb  = (unsigned short*)alloc(SZ_embb);
    unsigned short* EGb   = (unsigned short*)alloc(SZ_EGb);
    unsigned short* CstF  = (unsigned short*)alloc(SZ_Cst);
    const int nslot = batched ? 17 : 3;
    unsigned short* Hs    = (unsigned short*)alloc((size_t)nslot * pad(SZ_H));
    unsigned short* lgS   = (unsigned short*)alloc(SZ_LGS);
    float*          lossT = (float*)alloc(SZ_LT);
    const size_t HSLOT = pad(SZ_H) / 2;  // ushort elements per slot

    prep_all<<<19856, 256, 0, stream>>>(Wih, Whh, bih, bhh, Wout, emb, enc,
                                        Wihp, Whp8, biasp, Wob, embb,
                                        CstF, Hs, lossT);

    // EGb[v][n] = bf16(emb_bf16[v] @ Wihp[n]^T + biasp[n])   (512 x 4096)
    gemm_k<128, 128, 2><<<dim3(32, 4), 256, 0, stream>>>(
        embb, En, Wihp, En, En, biasp, nullptr, EGb, G4);

    if (batched) {
        for (int t = 0; t < Tn; t++)
            lstm8<<<dim3(16, 16), 1024, 0, stream>>>(
                Whp8, Hs + (size_t)t * HSLOT, EGb, target, t, CstF,
                Hs + (size_t)(t + 1) * HSLOT);
        logits512<<<512, 1024, 0, stream>>>(
            Hs + HSLOT, Wob, target, lossT);
        finalize_b<<<16, 256, 0, stream>>>(lossT, out);
    } else {
        for (int t = 0; t < Tn; t++) {
            unsigned short* hIn  = Hs + (size_t)(t % 3) * HSLOT;
            unsigned short* hOut = Hs + (size_t)((t + 1) % 3) * HSLOT;
            lstm8<<<dim3(16, 16), 1024, 0, stream>>>(
                Whp8, hIn, EGb, target, t, CstF, hOut);
            gemm_k<128, 64, 2><<<dim3(8, 32), 256, 0, stream>>>(
                hOut, Hn, Wob, Hn, Hn, nullptr, nullptr, lgS, Vn);
            lse_k<<<1024, 256, 0, stream>>>(lgS, target, t, lossT);
        }
        finalize_s<<<16, 256, 0, stream>>>(lossT, out);
    }
}

// Round 18
// 833.297 us; speedup vs baseline: 1.0137x; 1.0137x over previous
//
#include <hip/hip_runtime.h>
#include <hip/hip_bf16.h>
#include <stdint.h>

typedef __attribute__((ext_vector_type(8))) short bf16x8;
typedef __attribute__((ext_vector_type(4))) float f32x4;

#define DEV __device__ __forceinline__
#define MFMA16(a, b, c) __builtin_amdgcn_mfma_f32_16x16x32_bf16(a, b, c, 0, 0, 0)

static constexpr int Bn = 4096;    // batch
static constexpr int Tn = 16;      // time steps
static constexpr int Vn = 512;     // vocab
static constexpr int En = 512;     // embed dim
static constexpr int Hn = 1024;    // hidden
static constexpr int G4 = 4096;    // 4*H

DEV unsigned short f2bf(float f) {
    union { float f; uint32_t u; } v; v.f = f;
    return (unsigned short)((v.u + 0x7fffu + ((v.u >> 16) & 1u)) >> 16);
}
DEV float bf2f(unsigned short h) {
    union { uint32_t u; float f; } v; v.u = (uint32_t)h << 16; return v.f;
}
DEV float sigmoidf_(float x) { return 1.f / (1.f + __expf(-x)); }
DEV float tanhf_(float x)    { return 1.f - 2.f / (1.f + __expf(2.f * x)); }

DEV bf16x8 cvt8(const float* p) {
    f32x4 a = *(const f32x4*)p;
    f32x4 b = *(const f32x4*)(p + 4);
    bf16x8 o;
    o[0] = (short)f2bf(a[0]); o[1] = (short)f2bf(a[1]);
    o[2] = (short)f2bf(a[2]); o[3] = (short)f2bf(a[3]);
    o[4] = (short)f2bf(b[0]); o[5] = (short)f2bf(b[1]);
    o[6] = (short)f2bf(b[2]); o[7] = (short)f2bf(b[3]);
    return o;
}

#define GLOAD16(s, d) __builtin_amdgcn_global_load_lds( \
    (const __attribute__((address_space(1))) uint32_t*)(s), \
    (__attribute__((address_space(3))) uint32_t*)(d), 16, 0, 0)

// ---------------------------------------------------------------------------
// lstm8 (R14-exact, best known): 256x256-tile, BK=64, 1024 threads = 16
// waves (4M x 4N), 2-phase counted-vmcnt GEMM
//   gates^T = Whp8(perm,swz) @ Hin^T, K=1024  + fused LSTM epilogue.
// bf16 Cst + bf16 EGb, both read at EPILOGUE time only (R11 ledger lesson).
// Grid dim3(16,16): bx x-fastest -> XCD = bx%8 (B panel L2-local).
// LDS: A buf{0,1} @ ush {0,16384}, B buf{0,1} @ {32768,49152};
// XOR slot swizzle (r,c) -> r*64 + ((c>>3 ^ (r&7))<<3 | (c&7)).
// R17 lesson: 8-slot swizzle on 64-col rows is the ONLY conflict-free
// layout found; 4-slot/32-col variants 4-way-conflict on ds_read_b128.
// ---------------------------------------------------------------------------
__launch_bounds__(1024, 4)
__global__ void lstm8(const unsigned short* __restrict__ Whp8,
                      const unsigned short* __restrict__ Hin,
                      const unsigned short* __restrict__ EGb,
                      const int* __restrict__ target, int t,
                      unsigned short* __restrict__ CstF,
                      unsigned short* __restrict__ Hout)
{
    __shared__ __align__(16) unsigned short lds[65536];  // 128 KiB

    const int tid = threadIdx.x;
    const int l   = tid & 63;
    const int w   = tid >> 6;          // 0..15
    const int wm  = w >> 2, wn = w & 3;
    const int q   = l >> 4, c15 = l & 15;
    const int bx  = blockIdx.x, by = blockIdx.y;
    const int n0  = bx * 256;          // batch base
    const int U0  = by * 64;

    const int cBt = (((tid & 7) ^ ((tid >> 3) & 7)) << 3);
    const int sw0   = ((q ^ (c15 & 7)) << 3);
    const int offA0 = wm * 4096 + c15 * 64 + sw0;   // + i*1024 ; ^32 for ks1
    const int offB0 = wn * 4096 + c15 * 64 + sw0;   // + j*1024

    f32x4 acc[4][4];
#pragma unroll
    for (int i = 0; i < 4; i++)
#pragma unroll
        for (int j = 0; j < 4; j++) acc[i][j] = f32x4{0.f, 0.f, 0.f, 0.f};

    auto stA = [&](int kts, int cbuf) {
        const unsigned short* page =
            Whp8 + (((size_t)(by * 16 + kts) * 2) << 13);
#pragma unroll
        for (int h = 0; h < 2; h++)
            GLOAD16(page + h * 8192 + tid * 8,
                    &lds[cbuf * 16384 + h * 8192 + tid * 8]);
    };
    auto stB = [&](int kts, int cbuf) {
#pragma unroll
        for (int h = 0; h < 2; h++)
            GLOAD16(Hin + (size_t)(n0 + h * 128 + (tid >> 3)) * Hn
                        + kts * 64 + cBt,
                    &lds[32768 + cbuf * 16384 + h * 8192 + tid * 8]);
    };

    // ---- prologue: tile0 -> buf0, tile1 -> buf1 (4 loads each) ----
    stA(0, 0); stB(0, 0);
    stA(1, 1); stB(1, 1);
    asm volatile("s_waitcnt vmcnt(4)" ::: "memory");   // tile0 landed
    __builtin_amdgcn_s_barrier();

#pragma unroll 2
    for (int kt = 0; kt < 16; kt++) {
        const int cur = kt & 1;
        const unsigned short* Ab = &lds[cur * 16384];
        const unsigned short* Bb = &lds[32768 + cur * 16384];
        bf16x8 aF[4], bF[4];

        // ---- P1: ks = 0 ----
#pragma unroll
        for (int i = 0; i < 4; i++)
            aF[i] = *(const bf16x8*)&Ab[offA0 + i * 1024];
#pragma unroll
        for (int j = 0; j < 4; j++)
            bF[j] = *(const bf16x8*)&Bb[offB0 + j * 1024];
        __builtin_amdgcn_s_setprio(1);
#pragma unroll
        for (int i = 0; i < 4; i++)
#pragma unroll
            for (int j = 0; j < 4; j++)
                acc[i][j] = MFMA16(aF[i], bF[j], acc[i][j]);
        __builtin_amdgcn_s_setprio(0);

        // ---- P2: ks = 1 (slot offset ^32) ----
#pragma unroll
        for (int i = 0; i < 4; i++)
            aF[i] = *(const bf16x8*)&Ab[(offA0 ^ 32) + i * 1024];
#pragma unroll
        for (int j = 0; j < 4; j++)
            bF[j] = *(const bf16x8*)&Bb[(offB0 ^ 32) + j * 1024];
        __builtin_amdgcn_s_setprio(1);
#pragma unroll
        for (int i = 0; i < 4; i++)
#pragma unroll
            for (int j = 0; j < 4; j++)
                acc[i][j] = MFMA16(aF[i], bF[j], acc[i][j]);
        __builtin_amdgcn_s_setprio(0);
        __builtin_amdgcn_s_barrier();   // all reads of buf cur complete

        // ---- P3: stage kt+2 (clamped tail -> garbage, never read) ----
        const int kts = (kt + 2 < 16) ? (kt + 2) : 15;
        stA(kts, cur);
        stB(kts, cur);
        asm volatile("s_waitcnt vmcnt(4)" ::: "memory");  // kt+1 landed
        __builtin_amdgcn_s_barrier();
    }

    // ---- epilogue: LSTM pointwise (bf16 EGb gather, bf16 Cst RMW) ----
    int ids[4];
#pragma unroll
    for (int j = 0; j < 4; j++)
        ids[j] = (t > 0)
            ? target[(size_t)(n0 + wn * 64 + j * 16 + c15) * Tn + (t - 1)] : 0;

    unsigned short* sH = &lds[32768];  // B buf0: writes retired, none in flight
#pragma unroll
    for (int i = 0; i < 4; i++) {
        const int Uloc = wm * 16 + i * 4 + q;
#pragma unroll
        for (int j = 0; j < 4; j++) {
            uint2 egu = *(const uint2*)&EGb[(size_t)ids[j] * G4 + (U0 + Uloc) * 4];
            float e0 = bf2f((unsigned short)(egu.x & 0xffffu));
            float e1 = bf2f((unsigned short)(egu.x >> 16));
            float e2 = bf2f((unsigned short)(egu.y & 0xffffu));
            float e3 = bf2f((unsigned short)(egu.y >> 16));
            float ig = sigmoidf_(acc[i][j][0] + e0);
            float fg = sigmoidf_(acc[i][j][1] + e1);
            float gg = tanhf_  (acc[i][j][2] + e2);
            float og = sigmoidf_(acc[i][j][3] + e3);
            const size_t cidx =
                ((((size_t)(by * 16 + bx) * 16 + w) * 16 + i * 4 + j) << 6) + l;
            float cOld = bf2f(CstF[cidx]);
            float cNew = fg * cOld + ig * gg;
            float h    = og * tanhf_(cNew);
            CstF[cidx] = f2bf(cNew);
            const int bl = wn * 64 + j * 16 + c15;
            sH[bl * 64 + (Uloc ^ ((bl & 7) << 3))] = f2bf(h);
        }
    }
    __syncthreads();   // drains vmcnt(0) too (tail staging)
    {
        const int row  = tid >> 2;            // 0..255 batch-local
        const int part = tid & 3;
        size_t go = (size_t)(n0 + row) * Hn + U0;
#pragma unroll
        for (int s = 0; s < 2; s++) {
            const int slog = part * 2 + s;
            bf16x8 v = *(const bf16x8*)&sH[row * 64 + ((slog ^ (row & 7)) << 3)];
            *(bf16x8*)&Hout[go + slog * 8] = v;
        }
    }
}

// ---------------------------------------------------------------------------
// logits256 (R16-exact, best known): C[65536 h-rows][512 vocab] tiled
// 256x256, BK=64, 1024 threads = 16 waves (4M x 4N), per-wave 64x64,
// acc[4][4], 2-phase counted-vmcnt (4 gloads/tile -> vmcnt(4)).
// Grid 512: rb = bid&255, cb = bid>>8; bid and bid+256 share an XCD ->
// A tile L2-local. Per-row partial sum(exp) + target-logit; no max-subtract
// (|logit| <~ 58, f32-safe). 8-slot/64-col swizzle: conflict-free.
// ---------------------------------------------------------------------------
__launch_bounds__(1024, 4)
__global__ void logits256(const unsigned short* __restrict__ A,   // h history
                          const unsigned short* __restrict__ Wob,
                          const int* __restrict__ target,
                          float* __restrict__ partS,
                          float* __restrict__ partT)
{
    __shared__ __align__(16) unsigned short lds[65536];  // 128 KiB staging
    __shared__ float redS[4 * 256];
    __shared__ float redT[4 * 256];
    __shared__ int   tgL[256];

    const int tid = threadIdx.x;
    const int l   = tid & 63;
    const int w   = tid >> 6;          // 0..15
    const int wm  = w >> 2, wn = w & 3;
    const int q   = l >> 4, c15 = l & 15;
    const int bid = blockIdx.x;
    const int rb  = bid & 255, cb = bid >> 8;
    const int r0  = rb * 256;          // global row base (ra = t*Bn + m)
    const int v0  = cb * 256;          // vocab base

    if (tid < 256) {
        int ra = r0 + tid;
        tgL[tid] = target[(size_t)(ra & (Bn - 1)) * Tn + (ra >> 12)];
    }

    const int cBt = (((tid & 7) ^ ((tid >> 3) & 7)) << 3);
    const int sw0   = ((q ^ (c15 & 7)) << 3);
    const int offA0 = wm * 4096 + c15 * 64 + sw0;
    const int offB0 = wn * 4096 + c15 * 64 + sw0;

    f32x4 acc[4][4];
#pragma unroll
    for (int i = 0; i < 4; i++)
#pragma unroll
        for (int j = 0; j < 4; j++) acc[i][j] = f32x4{0.f, 0.f, 0.f, 0.f};

    auto stA = [&](int kts, int cbuf) {
#pragma unroll
        for (int h = 0; h < 2; h++)
            GLOAD16(A + (size_t)(r0 + h * 128 + (tid >> 3)) * Hn
                        + kts * 64 + cBt,
                    &lds[cbuf * 16384 + h * 8192 + tid * 8]);
    };
    auto stB = [&](int kts, int cbuf) {
#pragma unroll
        for (int h = 0; h < 2; h++)
            GLOAD16(Wob + (size_t)(v0 + h * 128 + (tid >> 3)) * Hn
                        + kts * 64 + cBt,
                    &lds[32768 + cbuf * 16384 + h * 8192 + tid * 8]);
    };

    stA(0, 0); stB(0, 0);
    stA(1, 1); stB(1, 1);
    asm volatile("s_waitcnt vmcnt(4)" ::: "memory");
    __builtin_amdgcn_s_barrier();

#pragma unroll 2
    for (int kt = 0; kt < 16; kt++) {
        const int cur = kt & 1;
        const unsigned short* Ab = &lds[cur * 16384];
        const unsigned short* Bb = &lds[32768 + cur * 16384];
        bf16x8 aF[4], bF[4];

#pragma unroll
        for (int i = 0; i < 4; i++)
            aF[i] = *(const bf16x8*)&Ab[offA0 + i * 1024];
#pragma unroll
        for (int j = 0; j < 4; j++)
            bF[j] = *(const bf16x8*)&Bb[offB0 + j * 1024];
        __builtin_amdgcn_s_setprio(1);
#pragma unroll
        for (int i = 0; i < 4; i++)
#pragma unroll
            for (int j = 0; j < 4; j++)
                acc[i][j] = MFMA16(aF[i], bF[j], acc[i][j]);
        __builtin_amdgcn_s_setprio(0);

#pragma unroll
        for (int i = 0; i < 4; i++)
            aF[i] = *(const bf16x8*)&Ab[(offA0 ^ 32) + i * 1024];
#pragma unroll
        for (int j = 0; j < 4; j++)
            bF[j] = *(const bf16x8*)&Bb[(offB0 ^ 32) + j * 1024];
        __builtin_amdgcn_s_setprio(1);
#pragma unroll
        for (int i = 0; i < 4; i++)
#pragma unroll
            for (int j = 0; j < 4; j++)
                acc[i][j] = MFMA16(aF[i], bF[j], acc[i][j]);
        __builtin_amdgcn_s_setprio(0);
        __builtin_amdgcn_s_barrier();

        const int kts = (kt + 2 < 16) ? (kt + 2) : 15;
        stA(kts, cur);
        stB(kts, cur);
        asm volatile("s_waitcnt vmcnt(4)" ::: "memory");
        __builtin_amdgcn_s_barrier();
    }

    // ---- epilogue: per-row partial Sexp / target-logit ----
#pragma unroll
    for (int i = 0; i < 4; i++)
#pragma unroll
        for (int rr = 0; rr < 4; rr++) {
            const int rloc = wm * 64 + i * 16 + q * 4 + rr;
            const int tg = tgL[rloc];
            float ps = 0.f, tv = 0.f;
#pragma unroll
            for (int j = 0; j < 4; j++) {
                float v = acc[i][j][rr];
                ps += __expf(v);
                int col = v0 + wn * 64 + j * 16 + c15;
                tv += (col == tg) ? v : 0.f;
            }
#pragma unroll
            for (int d = 1; d < 16; d <<= 1) {
                ps += __shfl_xor(ps, d);
                tv += __shfl_xor(tv, d);
            }
            if (c15 == 0) {
                redS[wn * 256 + rloc] = ps;
                redT[wn * 256 + rloc] = tv;
            }
        }
    __syncthreads();
    if (tid < 256) {
        float se = 0.f, tv = 0.f;
#pragma unroll
        for (int k = 0; k < 4; k++) {
            se += redS[k * 256 + tid];
            tv += redT[k * 256 + tid];
        }
        partS[(size_t)cb * (Bn * Tn) + r0 + tid] = se;
        partT[(size_t)cb * (Bn * Tn) + r0 + tid] = tv;
    }
}

// ---------------------------------------------------------------------------
// bf16 GEMM (m97-style): C[M][N] = A[M][K] * Bw[N][K]^T
// EPI=0: Out = acc (+biasp), f32.  EPI=2: Outb = bf16(acc (+biasp)).
// ---------------------------------------------------------------------------
template <int BM, int BN, int EPI>
__launch_bounds__(256, 2)
__global__ void gemm_k(const unsigned short* __restrict__ A, int lda,
                       const unsigned short* __restrict__ Bw, int ldb,
                       int K,
                       const float* __restrict__ biasp,
                       float* __restrict__ Out,
                       unsigned short* __restrict__ Outb, int ldo)
{
    constexpr int BK = 32;
    constexpr int WM = BM / 2, WN = BN / 2;
    constexpr int MI = WM / 16, NJ = WN / 16;

    __shared__ __align__(16) unsigned short sA[BM * BK];
    __shared__ __align__(16) unsigned short sB[BN * BK];

    const int tid = threadIdx.x;
    const int l   = tid & 63;
    const int w   = tid >> 6;
    const int wm  = w >> 1, wn = w & 1;
    const int m0  = blockIdx.y * BM;
    const int n0  = blockIdx.x * BN;

    f32x4 acc[MI][NJ];
#pragma unroll
    for (int i = 0; i < MI; i++)
#pragma unroll
        for (int j = 0; j < NJ; j++) acc[i][j] = f32x4{0.f, 0.f, 0.f, 0.f};

    const int srow = l >> 2;
    const int scol = (l & 3) * 8;
    const int q    = l >> 4;
    const int c15  = l & 15;

    for (int k0 = 0; k0 < K; k0 += BK) {
#pragma unroll
        for (int c = 0; c < BM / 64; c++)
            GLOAD16(A + (size_t)(m0 + c * 64 + w * 16 + srow) * lda + k0 + scol,
                    &sA[(c * 64 + w * 16) * BK]);
#pragma unroll
        for (int c = 0; c < BN / 64; c++)
            GLOAD16(Bw + (size_t)(n0 + c * 64 + w * 16 + srow) * ldb + k0 + scol,
                    &sB[(c * 64 + w * 16) * BK]);
        __syncthreads();

        bf16x8 aF[MI], bF[NJ];
#pragma unroll
        for (int i = 0; i < MI; i++)
            aF[i] = *(const bf16x8*)&sA[(wm * WM + i * 16 + c15) * BK + q * 8];
#pragma unroll
        for (int j = 0; j < NJ; j++)
            bF[j] = *(const bf16x8*)&sB[(wn * WN + j * 16 + c15) * BK + q * 8];
#pragma unroll
        for (int i = 0; i < MI; i++)
#pragma unroll
            for (int j = 0; j < NJ; j++)
                acc[i][j] = MFMA16(aF[i], bF[j], acc[i][j]);
        __syncthreads();
    }

#pragma unroll
    for (int j = 0; j < NJ; j++) {
        const int colp = n0 + wn * WN + j * 16 + c15;
        const float bj = biasp ? biasp[colp] : 0.f;
#pragma unroll
        for (int i = 0; i < MI; i++) {
            const size_t rb = (size_t)(m0 + wm * WM + i * 16 + 4 * q);
#pragma unroll
            for (int r = 0; r < 4; r++) {
                float vv = acc[i][j][r] + bj;
                if constexpr (EPI == 0) Out[(rb + r) * ldo + colp] = vv;
                else Outb[(rb + r) * ldo + colp] = f2bf(vv);
            }
        }
    }
}

// ---------------------------------------------------------------------------
// Fused prep + init: Wihp / Whp8 / bias / Wob / embb / Cst+Xh0+loss init.
// Block ranges: [0,1024) wih | [1024,3072) w8 | [3072,3088) bias
//   [3088,3344) wout | [3344,3472) emb | [3472,19856) init_state.
// ---------------------------------------------------------------------------
__global__ void prep_all(const float* __restrict__ Wih,
                         const float* __restrict__ Whh,
                         const float* __restrict__ bih,
                         const float* __restrict__ bhh,
                         const float* __restrict__ Wout,
                         const float* __restrict__ emb,
                         const float* __restrict__ enc,
                         unsigned short* __restrict__ Wihp,
                         unsigned short* __restrict__ Whp8,
                         float* __restrict__ biasp,
                         unsigned short* __restrict__ Wob,
                         unsigned short* __restrict__ embb,
                         unsigned short* __restrict__ CstF,
                         unsigned short* __restrict__ Xh0,
                         float* __restrict__ loss)
{
    const int b = blockIdx.x;
    if (b < 1024) {                       // Wihp[u*4+g][k] = W_ih[g*H+u][k]
        int i = b * 256 + threadIdx.x;    // 4096*64
        int n = i >> 6, kc = (i & 63) * 8;
        int g = n & 3, u = n >> 2;
        *(bf16x8*)&Wihp[(size_t)n * En + kc] =
            cvt8(Wih + (size_t)(g * Hn + u) * En + kc);
    } else if (b < 3072) {                // Whp8 slot-swizzled pages
        int idx = (b - 1024) * 256 + threadIdx.x;  // 0..524287
        int o = idx * 8;
        int p = o & 8191;
        int h = (o >> 13) & 1;
        int kt = (o >> 14) & 15;
        int by = o >> 18;
        int r = p >> 6;
        int slot = (p & 63) >> 3;
        int cl = ((slot ^ (r & 7)) << 3);
        int n = by * 256 + h * 128 + r;   // permuted gate row u*4+g
        int g = n & 3, u = n >> 2;
        *(bf16x8*)&Whp8[o] =
            cvt8(Whh + (size_t)(g * Hn + u) * Hn + kt * 64 + cl);
    } else if (b < 3088) {                // biasp
        int n = (b - 3072) * 256 + threadIdx.x;  // 4096
        int g = n & 3, u = n >> 2;
        biasp[n] = bih[g * Hn + u] + bhh[g * Hn + u];
    } else if (b < 3344) {                // Wob bf16
        int i = (b - 3088) * 256 + threadIdx.x;  // 65536
        size_t off = (size_t)i * 8;
        *(bf16x8*)&Wob[off] = cvt8(Wout + off);
    } else if (b < 3472) {                // embb bf16
        int i = (b - 3344) * 256 + threadIdx.x;  // 32768
        size_t off = (size_t)i * 8;
        *(bf16x8*)&embb[off] = cvt8(emb + off);
    } else {                              // init: Cst (epilogue layout) + Xh0
        int f = (b - 3472) * 256 + threadIdx.x;  // 0 .. 4194303
        int l = f & 63, q = l >> 4, c15 = l & 15;
        int ij = (f >> 6) & 15, i = ij >> 2, j = ij & 3;
        int w = (f >> 10) & 15, wm = w >> 2, wn = w & 3;
        int bx = (f >> 14) & 15, by = (f >> 18) & 15;
        int bb = bx * 256 + wn * 64 + j * 16 + c15;
        int U  = by * 64 + wm * 16 + i * 4 + q;
        CstF[f] = f2bf(enc[(size_t)bb * Hn + U]);
        if (f < Bn * Hn / 8) {
            int m = f >> 7, u8 = (f & 127) * 8;
            *(bf16x8*)&Xh0[(size_t)m * Hn + u8] =
                cvt8(enc + (size_t)m * Hn + u8);
        }
        if (f < Bn) loss[f] = 0.f;
    }
}

// LSE + NLL over bf16 logits (fallback path).
__global__ void lse_k(const unsigned short* __restrict__ lg,
                      const int* __restrict__ target, int t,
                      float* __restrict__ lossOut)
{
    int w = threadIdx.x >> 6, l = threadIdx.x & 63;
    int ra = blockIdx.x * 4 + w;
    const unsigned short* row = lg + (size_t)ra * Vn;
    bf16x8 v = *(const bf16x8*)&row[l * 8];
    float x0 = bf2f((unsigned short)v[0]), x1 = bf2f((unsigned short)v[1]);
    float x2 = bf2f((unsigned short)v[2]), x3 = bf2f((unsigned short)v[3]);
    float x4 = bf2f((unsigned short)v[4]), x5 = bf2f((unsigned short)v[5]);
    float x6 = bf2f((unsigned short)v[6]), x7 = bf2f((unsigned short)v[7]);
    float mx = fmaxf(fmaxf(fmaxf(x0, x1), fmaxf(x2, x3)),
                     fmaxf(fmaxf(x4, x5), fmaxf(x6, x7)));
#pragma unroll
    for (int d = 1; d < 64; d <<= 1) mx = fmaxf(mx, __shfl_xor(mx, d));
    float se = __expf(x0 - mx) + __expf(x1 - mx) + __expf(x2 - mx) +
               __expf(x3 - mx) + __expf(x4 - mx) + __expf(x5 - mx) +
               __expf(x6 - mx) + __expf(x7 - mx);
#pragma unroll
    for (int d = 1; d < 64; d <<= 1) se += __shfl_xor(se, d);
    if (l == 0) {
        int tg = target[(size_t)ra * Tn + t];
        lossOut[ra] += (mx + __logf(se)) - bf2f(row[tg]);
    }
}

// Batched finalize from partS/partT (2 vocab halves).
__global__ void finalize_p(const float* __restrict__ partS,
                           const float* __restrict__ partT,
                           float* __restrict__ out)
{
    int m = blockIdx.x * 256 + threadIdx.x;
    float s = 0.f;
#pragma unroll
    for (int k = 0; k < 16; k++) {
        size_t ra = (size_t)k * Bn + m;
        float se = partS[ra] + partS[(size_t)(Bn * Tn) + ra];
        float tv = partT[ra] + partT[(size_t)(Bn * Tn) + ra];
        s += __logf(se) - tv;
    }
    out[m] = s * (1.f / 16.f);
}

__global__ void finalize_s(const float* __restrict__ loss,
                           float* __restrict__ out)
{
    int m = blockIdx.x * 256 + threadIdx.x;
    out[m] = loss[m] * (1.f / 16.f);
}

// ---------------------------------------------------------------------------
extern "C" void kernel_launch(void* const* d_in, const int* in_sizes, int n_in,
                              void* d_out, int out_size, void* d_ws, size_t ws_size,
                              hipStream_t stream)
{
    const float* enc    = (const float*)d_in[0];
    const int*   target = (const int*)d_in[1];
    const float* emb    = (const float*)d_in[2];
    const float* Wih    = (const float*)d_in[3];
    const float* Whh    = (const float*)d_in[4];
    const float* bih    = (const float*)d_in[5];
    const float* bhh    = (const float*)d_in[6];
    const float* Wout   = (const float*)d_in[7];
    float* out = (float*)d_out;
    (void)in_sizes; (void)n_in; (void)out_size;

    constexpr size_t SZ_Wihp  = (size_t)G4 * En * 2;
    constexpr size_t SZ_Whp8  = (size_t)G4 * Hn * 2;
    constexpr size_t SZ_Wob   = (size_t)Vn * Hn * 2;
    constexpr size_t SZ_biasp = (size_t)G4 * 4;
    constexpr size_t SZ_embb  = (size_t)Vn * En * 2;
    constexpr size_t SZ_EGb   = (size_t)Vn * G4 * 2;      // bf16
    constexpr size_t SZ_Cst   = (size_t)Bn * Hn * 2;      // bf16
    constexpr size_t SZ_H     = (size_t)Bn * Hn * 2;
    constexpr size_t SZ_LGS   = (size_t)Bn * Vn * 2;
    constexpr size_t SZ_PART  = (size_t)2 * Bn * Tn * 4;  // [cb][row]
    auto pad = [](size_t b) { return (b + 255) & ~(size_t)255; };
    const size_t fixed = pad(SZ_Wihp) + pad(SZ_Whp8) + pad(SZ_Wob) +
                         pad(SZ_biasp) + pad(SZ_embb) + pad(SZ_EGb) +
                         pad(SZ_Cst);
    const size_t needB = fixed + 17 * pad(SZ_H) + pad(SZ_LGS) +
                         2 * pad(SZ_PART);
    const bool batched = ws_size >= needB;

    size_t off = 0;
    char* base = (char*)d_ws;
    auto alloc = [&](size_t bytes) -> void* {
        void* p = base + off; off += pad(bytes); return p;
    };
    unsigned short* Wihp  = (unsigned short*)alloc(SZ_Wihp);
    unsigned short* Whp8  = (unsigned short*)alloc(SZ_Whp8);
    unsigned short* Wob   = (unsigned short*)alloc(SZ_Wob);
    float*          biasp = (float*)alloc(SZ_biasp);
    unsigned short* embb  = (unsigned short*)alloc(SZ_embb);
    unsigned short* EGb   = (unsigned short*)alloc(SZ_EGb);
    unsigned short* CstF  = (unsigned short*)alloc(SZ_Cst);
    const int nslot = batched ? 17 : 3;
    unsigned short* Hs    = (unsigned short*)alloc((size_t)nslot * pad(SZ_H));
    unsigned short* lgS   = (unsigned short*)alloc(SZ_LGS);
    float*          partS = (float*)alloc(SZ_PART);
    float*          partT = (float*)alloc(SZ_PART);
    const size_t HSLOT = pad(SZ_H) / 2;  // ushort elements per slot

    prep_all<<<19856, 256, 0, stream>>>(Wih, Whh, bih, bhh, Wout, emb, enc,
                                        Wihp, Whp8, biasp, Wob, embb,
                                        CstF, Hs, partS);

    // EGb[v][n] = bf16(emb_bf16[v] @ Wihp[n]^T + biasp[n])   (512 x 4096)
    gemm_k<128, 128, 2><<<dim3(32, 4), 256, 0, stream>>>(
        embb, En, Wihp, En, En, biasp, nullptr, EGb, G4);

    if (batched) {
        for (int t = 0; t < Tn; t++)
            lstm8<<<dim3(16, 16), 1024, 0, stream>>>(
                Whp8, Hs + (size_t)t * HSLOT, EGb, target, t, CstF,
                Hs + (size_t)(t + 1) * HSLOT);
        logits256<<<512, 1024, 0, stream>>>(
            Hs + HSLOT, Wob, target, partS, partT);
        finalize_p<<<16, 256, 0, stream>>>(partS, partT, out);
    } else {
        for (int t = 0; t < Tn; t++) {
            unsigned short* hIn  = Hs + (size_t)(t % 3) * HSLOT;
            unsigned short* hOut = Hs + (size_t)((t + 1) % 3) * HSLOT;
            lstm8<<<dim3(16, 16), 1024, 0, stream>>>(
                Whp8, hIn, EGb, target, t, CstF, hOut);
            gemm_k<128, 64, 2><<<dim3(8, 32), 256, 0, stream>>>(
                hOut, Hn, Wob, Hn, Hn, nullptr, nullptr, lgS, Vn);
            lse_k<<<1024, 256, 0, stream>>>(lgS, target, t, partS);
        }
        finalize_s<<<16, 256, 0, stream>>>(partS, out);
    }
}